// Round 12
// baseline (783.587 us; speedup 1.0000x reference)
//
#include <hip/hip_runtime.h>

// LightplaneSplatter: trilinear scatter-splat of per-ray encodings (C=16)
// into a (1,128,128,128,16) fp32 grid.
//
// Round 12: register-gather accum.
//   R10 (2-wave, plain LDS RMW) = 351us latency-bound; R11 (8-wave z-slab)
//   = 457us redundant-walk-bound. Invert the loop: each of 512 threads owns
//   ONE grid point x ALL 16 channels in 16 VGPRs; records staged to LDS once
//   (coalesced) and scanned as wave-broadcast reads. Footprint test ~10 VALU
//   ops; z-engagement test is wave-uniform (wave = z-layer) so 75% of
//   records skip the hit body entirely. Zero atomics, zero LDS RMW, fully
//   coalesced 64B/thread flush.

#define NS   64
#define NSI  8
#define ST   (NS + NSI)   // 72
#define GD   128
#define GH   128
#define GW   128
#define GC   16
#define DISP_INF 1e-4f

#define NTT   16                    // tiles per axis (8 points each)
#define NBINS (NTT * NTT * NTT)     // 4096
#define CHK   512                   // samples per chunk
#define MULTI_FLAG 0x80000000u
#define ACC_THREADS 512             // one thread per tile point

// ---------------------------------------------------------------------------
__device__ __forceinline__ bool compute_sample(
    const float* __restrict__ dirs, const float* __restrict__ orig,
    const float* __restrict__ nearv, const float* __restrict__ farv,
    int ray, int s,
    int& ix, int& iy, int& iz, float& fx, float& fy, float& fz)
{
    float nr = nearv[ray], fr = farv[ray];
    float t;
    if (s < NS) {
        float frac = ((float)s + 0.5f) * (1.0f / (float)NS);
        t = nr + (fr - nr) * frac;
    } else {
        float j    = (float)(s - NS + 1) * (1.0f / (float)NSI);
        float invf = 1.0f / fr;
        float disp = invf + (DISP_INF - invf) * j;
        t = 1.0f / disp;
    }
    float px = orig[ray*3+0] + t * dirs[ray*3+0];
    float py = orig[ray*3+1] + t * dirs[ray*3+1];
    float pz = orig[ray*3+2] + t * dirs[ray*3+2];
    float vx = (px + 1.0f) * 0.5f * 127.0f;
    float vy = (py + 1.0f) * 0.5f * 127.0f;
    float vz = (pz + 1.0f) * 0.5f * 127.0f;
    float bx = floorf(vx), by = floorf(vy), bz = floorf(vz);
    fx = vx - bx; fy = vy - by; fz = vz - bz;
    ix = (int)bx; iy = (int)by; iz = (int)bz;
    return !(ix < -1 || ix > GW - 1 ||
             iy < -1 || iy > GH - 1 ||
             iz < -1 || iz > GD - 1);
}

// Tile range touched by base cell i along one axis (i in [-1, 127]).
__device__ __forceinline__ void tile_range(int i, int& t0, int& t1)
{
    t0 = (i < 0 ? 0 : i) >> 3;
    t1 = (i + 1 > 127 ? 127 : i + 1) >> 3;
}

// ---------------------------------------------------------------------------
// Pass A: per-tile sample counts (with duplication for boundary footprints).
__global__ __launch_bounds__(256) void count_kernel(
    const float* __restrict__ dirs, const float* __restrict__ orig,
    const float* __restrict__ nearv, const float* __restrict__ farv,
    int* __restrict__ counts, int total)
{
    __shared__ int h[NBINS];
    for (int i = threadIdx.x; i < NBINS; i += 256) h[i] = 0;
    __syncthreads();
    for (int idx = blockIdx.x * 256 + threadIdx.x; idx < total;
         idx += gridDim.x * 256) {
        int ray = idx / ST, s = idx - (idx / ST) * ST;
        int ix, iy, iz; float fx, fy, fz;
        if (!compute_sample(dirs, orig, nearv, farv, ray, s, ix, iy, iz, fx, fy, fz))
            continue;
        int tx0, tx1, ty0, ty1, tz0, tz1;
        tile_range(ix, tx0, tx1); tile_range(iy, ty0, ty1); tile_range(iz, tz0, tz1);
        for (int tz = tz0; tz <= tz1; ++tz)
            for (int ty = ty0; ty <= ty1; ++ty)
                for (int tx = tx0; tx <= tx1; ++tx)
                    atomicAdd(&h[(tz * NTT + ty) * NTT + tx], 1);
    }
    __syncthreads();
    for (int i = threadIdx.x; i < NBINS; i += 256)
        if (h[i]) atomicAdd(&counts[i], h[i]);
}

// ---------------------------------------------------------------------------
// Pass B: scan counts -> offsets/cursor; emit chunk table.
__global__ __launch_bounds__(256) void scan_kernel(
    const int* __restrict__ counts, int* __restrict__ offsets,
    int* __restrict__ cursor, unsigned int* __restrict__ chunk_info,
    int* __restrict__ nck)
{
    __shared__ int p1[256], p2[256];
    const int CH = NBINS / 256;  // 16
    int tid = threadIdx.x;
    int base = tid * CH;
    int s1 = 0, s2 = 0;
    for (int i = 0; i < CH; ++i) {
        int c = counts[base + i];
        s1 += c;
        s2 += (c + CHK - 1) / CHK;
    }
    p1[tid] = s1; p2[tid] = s2;
    __syncthreads();
    if (tid == 0) {
        int a1 = 0, a2 = 0;
        for (int i = 0; i < 256; ++i) {
            int v1 = p1[i], v2 = p2[i];
            p1[i] = a1; p2[i] = a2;
            a1 += v1; a2 += v2;
        }
        nck[0] = a2;
    }
    __syncthreads();
    int run = p1[tid];
    int crun = p2[tid];
    for (int i = 0; i < CH; ++i) {
        int bin = base + i;
        int c = counts[bin];
        offsets[bin] = run;
        cursor[bin]  = run;
        int nc = (c + CHK - 1) / CHK;
        unsigned int mf = (nc > 1) ? MULTI_FLAG : 0u;
        for (int k = 0; k < nc; ++k)
            chunk_info[crun + k] = (unsigned int)bin | ((unsigned int)k << 12) | mf;
        crun += nc;
        run += c;
    }
}

// ---------------------------------------------------------------------------
// Pass C: scatter fat records into per-tile lists.
// Record: float4 { uint pack = ray<<12 | (lz0+1)<<8 | (ly0+1)<<4 | (lx0+1),
//                  fx, fy, fz }  with l*0 = base cell relative to tile origin.
__global__ __launch_bounds__(256) void scatter_kernel(
    const float* __restrict__ dirs, const float* __restrict__ orig,
    const float* __restrict__ nearv, const float* __restrict__ farv,
    int* __restrict__ cursor, float4* __restrict__ recs, int total, int cap)
{
    int idx = blockIdx.x * 256 + threadIdx.x;
    if (idx >= total) return;
    int ray = idx / ST, s = idx - (idx / ST) * ST;
    int ix, iy, iz; float fx, fy, fz;
    if (!compute_sample(dirs, orig, nearv, farv, ray, s, ix, iy, iz, fx, fy, fz))
        return;
    int tx0, tx1, ty0, ty1, tz0, tz1;
    tile_range(ix, tx0, tx1); tile_range(iy, ty0, ty1); tile_range(iz, tz0, tz1);
    for (int tz = tz0; tz <= tz1; ++tz)
        for (int ty = ty0; ty <= ty1; ++ty)
            for (int tx = tx0; tx <= tx1; ++tx) {
                int bin = (tz * NTT + ty) * NTT + tx;
                int slot = atomicAdd(&cursor[bin], 1);
                if (slot < cap) {
                    unsigned int pk = ((unsigned int)ray << 12)
                                    | ((unsigned int)(iz - (tz << 3) + 1) << 8)
                                    | ((unsigned int)(iy - (ty << 3) + 1) << 4)
                                    |  (unsigned int)(ix - (tx << 3) + 1);
                    recs[slot] = make_float4(__uint_as_float(pk), fx, fy, fz);
                }
            }
}

// ---------------------------------------------------------------------------
// Pass D: one block (512 threads) per chunk; thread p owns tile point p and
// all 16 channels in registers. Scan staged records; accumulate on footprint
// hit; coalesced 64B/thread flush. No LDS RMW, no atomics in the loop.
__global__ __launch_bounds__(ACC_THREADS, 8) void accum_kernel(
    const float* __restrict__ enc,
    const int* __restrict__ offsets, const int* __restrict__ counts,
    const float4* __restrict__ recs, const unsigned int* __restrict__ chunk_info,
    const int* __restrict__ nck,
    float* __restrict__ grid)
{
    if ((int)blockIdx.x >= nck[0]) return;
    unsigned int info = chunk_info[blockIdx.x];
    int bin  = (int)(info & 0xFFFu);
    int k    = (int)((info >> 12) & 0x7FFFFu);
    bool multi = (info & MULTI_FLAG) != 0;
    int cnt  = counts[bin];
    int start = offsets[bin] + k * CHK;
    int n = cnt - k * CHK; if (n > CHK) n = CHK;

    int tx = bin & 15, ty = (bin >> 4) & 15, tz = bin >> 8;
    int gx0 = tx << 3, gy0 = ty << 3, gz0 = tz << 3;

    __shared__ float4 srec[CHK];          // 8 KB
    int tid = threadIdx.x;
    if (tid < n) srec[tid] = recs[start + tid];
    __syncthreads();

    // My point: wave = z-layer (tid>>6), so the dz test is wave-uniform.
    int mlx = tid & 7, mly = (tid >> 3) & 7, mlz = tid >> 6;

    float4 a0 = make_float4(0.f,0.f,0.f,0.f);
    float4 a1 = a0, a2 = a0, a3 = a0;

    for (int r = 0; r < n; ++r) {
        float4 R = srec[r];                      // wave-broadcast LDS read
        unsigned int pk = __float_as_uint(R.x);
        unsigned int dz = (unsigned int)(mlz - ((int)((pk >> 8) & 15u) - 1));
        if (dz <= 1u) {                          // wave-uniform branch
            unsigned int dx = (unsigned int)(mlx - ((int)(pk & 15u) - 1));
            unsigned int dy = (unsigned int)(mly - ((int)((pk >> 4) & 15u) - 1));
            if (dx <= 1u && dy <= 1u) {          // my point is in footprint
                float wx = dx ? R.y : 1.0f - R.y;
                float wy = dy ? R.z : 1.0f - R.z;
                float wzv = dz ? R.w : 1.0f - R.w;
                float w = wx * wy * wzv;
                const float4* e4 = (const float4*)(enc + (pk >> 12) * GC);
                float4 e;
                e = e4[0]; a0.x += w*e.x; a0.y += w*e.y; a0.z += w*e.z; a0.w += w*e.w;
                e = e4[1]; a1.x += w*e.x; a1.y += w*e.y; a1.z += w*e.z; a1.w += w*e.w;
                e = e4[2]; a2.x += w*e.x; a2.y += w*e.y; a2.z += w*e.z; a2.w += w*e.w;
                e = e4[3]; a3.x += w*e.x; a3.y += w*e.y; a3.z += w*e.z; a3.w += w*e.w;
            }
        }
    }

    // Flush: thread owns 64 contiguous bytes at its point.
    size_t gf = (((size_t)((gz0 + mlz) * GH + gy0 + mly)) * GW + gx0 + mlx) * GC;
    if (!multi) {
        // Exclusive tile: zero-skipped float4 stores (grid pre-zeroed).
        if (a0.x!=0.f || a0.y!=0.f || a0.z!=0.f || a0.w!=0.f) *(float4*)&grid[gf+ 0] = a0;
        if (a1.x!=0.f || a1.y!=0.f || a1.z!=0.f || a1.w!=0.f) *(float4*)&grid[gf+ 4] = a1;
        if (a2.x!=0.f || a2.y!=0.f || a2.z!=0.f || a2.w!=0.f) *(float4*)&grid[gf+ 8] = a2;
        if (a3.x!=0.f || a3.y!=0.f || a3.z!=0.f || a3.w!=0.f) *(float4*)&grid[gf+12] = a3;
    } else {
        // Shared tile: zero-skipped global atomics.
        float v;
        v=a0.x; if(v!=0.f) unsafeAtomicAdd(&grid[gf+ 0], v);
        v=a0.y; if(v!=0.f) unsafeAtomicAdd(&grid[gf+ 1], v);
        v=a0.z; if(v!=0.f) unsafeAtomicAdd(&grid[gf+ 2], v);
        v=a0.w; if(v!=0.f) unsafeAtomicAdd(&grid[gf+ 3], v);
        v=a1.x; if(v!=0.f) unsafeAtomicAdd(&grid[gf+ 4], v);
        v=a1.y; if(v!=0.f) unsafeAtomicAdd(&grid[gf+ 5], v);
        v=a1.z; if(v!=0.f) unsafeAtomicAdd(&grid[gf+ 6], v);
        v=a1.w; if(v!=0.f) unsafeAtomicAdd(&grid[gf+ 7], v);
        v=a2.x; if(v!=0.f) unsafeAtomicAdd(&grid[gf+ 8], v);
        v=a2.y; if(v!=0.f) unsafeAtomicAdd(&grid[gf+ 9], v);
        v=a2.z; if(v!=0.f) unsafeAtomicAdd(&grid[gf+10], v);
        v=a2.w; if(v!=0.f) unsafeAtomicAdd(&grid[gf+11], v);
        v=a3.x; if(v!=0.f) unsafeAtomicAdd(&grid[gf+12], v);
        v=a3.y; if(v!=0.f) unsafeAtomicAdd(&grid[gf+13], v);
        v=a3.z; if(v!=0.f) unsafeAtomicAdd(&grid[gf+14], v);
        v=a3.w; if(v!=0.f) unsafeAtomicAdd(&grid[gf+15], v);
    }
}

// ---------------------------------------------------------------------------
// Fallback: direct atomic splat (round-1 kernel) if d_ws is too small.
__global__ __launch_bounds__(256) void splat_direct(
    const float* __restrict__ dirs, const float* __restrict__ orig,
    const float* __restrict__ nearv, const float* __restrict__ farv,
    const float* __restrict__ enc,
    float* __restrict__ grid, int n_rays)
{
    int gt = blockIdx.x * blockDim.x + threadIdx.x;
    int group = gt >> 4;
    int c = gt & 15;
    if (group >= n_rays * ST) return;
    int ray = group / ST;
    int s   = group - ray * ST;
    int ix, iy, iz; float fx, fy, fz;
    if (!compute_sample(dirs, orig, nearv, farv, ray, s, ix, iy, iz, fx, fy, fz))
        return;
    float ev = enc[ray * GC + c];
    float gx0 = 1.0f - fx, gy0 = 1.0f - fy, gz0 = 1.0f - fz;
    #pragma unroll
    for (int corner = 0; corner < 8; ++corner) {
        int cx = corner & 1, cy = (corner >> 1) & 1, cz = (corner >> 2) & 1;
        int jx = ix + cx, jy = iy + cy, jz = iz + cz;
        if (jx < 0 || jx >= GW || jy < 0 || jy >= GH || jz < 0 || jz >= GD) continue;
        float w = (cx ? fx : gx0) * (cy ? fy : gy0) * (cz ? fz : gz0);
        unsafeAtomicAdd(&grid[((jz * GH + jy) * GW + jx) * GC + c], w * ev);
    }
}

// ---------------------------------------------------------------------------
extern "C" void kernel_launch(void* const* d_in, const int* in_sizes, int n_in,
                              void* d_out, int out_size, void* d_ws, size_t ws_size,
                              hipStream_t stream) {
    const float* dirs  = (const float*)d_in[0];
    const float* orig  = (const float*)d_in[1];
    const float* nearv = (const float*)d_in[2];
    const float* farv  = (const float*)d_in[3];
    const float* enc   = (const float*)d_in[4];
    float* out = (float*)d_out;

    int n_rays = in_sizes[2];
    int total  = n_rays * ST;

    hipMemsetAsync(out, 0, (size_t)out_size * sizeof(float), stream);

    // Workspace layout: [counts|offsets|cursor|nck|chunk_info| (align16) recs]
    int cap = total + total / 2;                 // record capacity (~1.5x)
    int maxck = NBINS + cap / CHK + 2;           // chunk-table bound
    size_t prefix_ints = (size_t)NBINS * 3 + 1 + (size_t)maxck;
    prefix_ints = (prefix_ints + 3) & ~(size_t)3;        // align recs to 16 B
    size_t need = prefix_ints * 4 + (size_t)cap * 16;

    if (ws_size < need || n_rays >= (1 << 20)) {
        long long tthreads = (long long)total * 16;
        int blocks = (int)((tthreads + 255) / 256);
        splat_direct<<<blocks, 256, 0, stream>>>(dirs, orig, nearv, farv, enc,
                                                 out, n_rays);
        return;
    }

    int* counts  = (int*)d_ws;
    int* offsets = counts + NBINS;
    int* cursor  = offsets + NBINS;
    int* nck     = cursor + NBINS;
    unsigned int* chunk_info = (unsigned int*)(nck + 1);
    float4* recs = (float4*)((int*)d_ws + prefix_ints);

    hipMemsetAsync(counts, 0, NBINS * sizeof(int), stream);
    count_kernel<<<1024, 256, 0, stream>>>(dirs, orig, nearv, farv, counts, total);
    scan_kernel<<<1, 256, 0, stream>>>(counts, offsets, cursor, chunk_info, nck);
    scatter_kernel<<<(total + 255) / 256, 256, 0, stream>>>(
        dirs, orig, nearv, farv, cursor, recs, total, cap);
    accum_kernel<<<maxck, ACC_THREADS, 0, stream>>>(
        enc, offsets, counts, recs, chunk_info, nck, out);
}

// Round 13
// 404.262 us; speedup vs baseline: 1.9383x; 1.9383x over previous
//
#include <hip/hip_runtime.h>

// LightplaneSplatter: trilinear scatter-splat of per-ray encodings (C=16)
// into a (1,128,128,128,16) fp32 grid.
//
// Round 13: z-bucket counting sort inside the accum block.
//   R10 (no redundancy, 2 waves) = 351us latency-bound; R11 (8 waves, 4.5x
//   redundant decode) = 457us; R12 (512-thr scan, strided flush) = 567us
//   with 3x write blowup. Fix: stage chunk records to LDS, counting-sort by
//   z-bucket (lz0+1, already in the pack), wave w walks ONLY buckets w,w+1
//   (records engaging its z-layer): one 64-lane op each (4 xy-corners x 16
//   channels), plain LDS RMW, no atomics, no redundant decode. CHK=1024.
//   Flush restored to R11's contiguous wave pattern (lane-adjacent =
//   address-adjacent; R12's 64B/lane stride tripled HBM writes).

#define NS   64
#define NSI  8
#define ST   (NS + NSI)   // 72
#define GD   128
#define GH   128
#define GW   128
#define GC   16
#define DISP_INF 1e-4f

#define NTT   16                    // tiles per axis (8 points each)
#define NBINS (NTT * NTT * NTT)     // 4096
#define TILE_FL (8 * 8 * 8 * GC)    // 8192 floats = 32 KB
#define CHK   1024                  // samples per chunk
#define MULTI_FLAG 0x80000000u
#define ACC_THREADS 512             // 8 waves, one z-layer each

// ---------------------------------------------------------------------------
__device__ __forceinline__ bool compute_sample(
    const float* __restrict__ dirs, const float* __restrict__ orig,
    const float* __restrict__ nearv, const float* __restrict__ farv,
    int ray, int s,
    int& ix, int& iy, int& iz, float& fx, float& fy, float& fz)
{
    float nr = nearv[ray], fr = farv[ray];
    float t;
    if (s < NS) {
        float frac = ((float)s + 0.5f) * (1.0f / (float)NS);
        t = nr + (fr - nr) * frac;
    } else {
        float j    = (float)(s - NS + 1) * (1.0f / (float)NSI);
        float invf = 1.0f / fr;
        float disp = invf + (DISP_INF - invf) * j;
        t = 1.0f / disp;
    }
    float px = orig[ray*3+0] + t * dirs[ray*3+0];
    float py = orig[ray*3+1] + t * dirs[ray*3+1];
    float pz = orig[ray*3+2] + t * dirs[ray*3+2];
    float vx = (px + 1.0f) * 0.5f * 127.0f;
    float vy = (py + 1.0f) * 0.5f * 127.0f;
    float vz = (pz + 1.0f) * 0.5f * 127.0f;
    float bx = floorf(vx), by = floorf(vy), bz = floorf(vz);
    fx = vx - bx; fy = vy - by; fz = vz - bz;
    ix = (int)bx; iy = (int)by; iz = (int)bz;
    return !(ix < -1 || ix > GW - 1 ||
             iy < -1 || iy > GH - 1 ||
             iz < -1 || iz > GD - 1);
}

// Tile range touched by base cell i along one axis (i in [-1, 127]).
__device__ __forceinline__ void tile_range(int i, int& t0, int& t1)
{
    t0 = (i < 0 ? 0 : i) >> 3;
    t1 = (i + 1 > 127 ? 127 : i + 1) >> 3;
}

// ---------------------------------------------------------------------------
// Pass A: per-tile sample counts (with duplication for boundary footprints).
__global__ __launch_bounds__(256) void count_kernel(
    const float* __restrict__ dirs, const float* __restrict__ orig,
    const float* __restrict__ nearv, const float* __restrict__ farv,
    int* __restrict__ counts, int total)
{
    __shared__ int h[NBINS];
    for (int i = threadIdx.x; i < NBINS; i += 256) h[i] = 0;
    __syncthreads();
    for (int idx = blockIdx.x * 256 + threadIdx.x; idx < total;
         idx += gridDim.x * 256) {
        int ray = idx / ST, s = idx - (idx / ST) * ST;
        int ix, iy, iz; float fx, fy, fz;
        if (!compute_sample(dirs, orig, nearv, farv, ray, s, ix, iy, iz, fx, fy, fz))
            continue;
        int tx0, tx1, ty0, ty1, tz0, tz1;
        tile_range(ix, tx0, tx1); tile_range(iy, ty0, ty1); tile_range(iz, tz0, tz1);
        for (int tz = tz0; tz <= tz1; ++tz)
            for (int ty = ty0; ty <= ty1; ++ty)
                for (int tx = tx0; tx <= tx1; ++tx)
                    atomicAdd(&h[(tz * NTT + ty) * NTT + tx], 1);
    }
    __syncthreads();
    for (int i = threadIdx.x; i < NBINS; i += 256)
        if (h[i]) atomicAdd(&counts[i], h[i]);
}

// ---------------------------------------------------------------------------
// Pass B: scan counts -> offsets/cursor; emit chunk table.
__global__ __launch_bounds__(256) void scan_kernel(
    const int* __restrict__ counts, int* __restrict__ offsets,
    int* __restrict__ cursor, unsigned int* __restrict__ chunk_info,
    int* __restrict__ nck)
{
    __shared__ int p1[256], p2[256];
    const int CH = NBINS / 256;  // 16
    int tid = threadIdx.x;
    int base = tid * CH;
    int s1 = 0, s2 = 0;
    for (int i = 0; i < CH; ++i) {
        int c = counts[base + i];
        s1 += c;
        s2 += (c + CHK - 1) / CHK;
    }
    p1[tid] = s1; p2[tid] = s2;
    __syncthreads();
    if (tid == 0) {
        int a1 = 0, a2 = 0;
        for (int i = 0; i < 256; ++i) {
            int v1 = p1[i], v2 = p2[i];
            p1[i] = a1; p2[i] = a2;
            a1 += v1; a2 += v2;
        }
        nck[0] = a2;
    }
    __syncthreads();
    int run = p1[tid];
    int crun = p2[tid];
    for (int i = 0; i < CH; ++i) {
        int bin = base + i;
        int c = counts[bin];
        offsets[bin] = run;
        cursor[bin]  = run;
        int nc = (c + CHK - 1) / CHK;
        unsigned int mf = (nc > 1) ? MULTI_FLAG : 0u;
        for (int k = 0; k < nc; ++k)
            chunk_info[crun + k] = (unsigned int)bin | ((unsigned int)k << 12) | mf;
        crun += nc;
        run += c;
    }
}

// ---------------------------------------------------------------------------
// Pass C: scatter fat records into per-tile lists.
// Record: float4 { uint pack = ray<<12 | (lz0+1)<<8 | (ly0+1)<<4 | (lx0+1),
//                  fx, fy, fz }  with l*0 = base cell relative to tile origin.
__global__ __launch_bounds__(256) void scatter_kernel(
    const float* __restrict__ dirs, const float* __restrict__ orig,
    const float* __restrict__ nearv, const float* __restrict__ farv,
    int* __restrict__ cursor, float4* __restrict__ recs, int total, int cap)
{
    int idx = blockIdx.x * 256 + threadIdx.x;
    if (idx >= total) return;
    int ray = idx / ST, s = idx - (idx / ST) * ST;
    int ix, iy, iz; float fx, fy, fz;
    if (!compute_sample(dirs, orig, nearv, farv, ray, s, ix, iy, iz, fx, fy, fz))
        return;
    int tx0, tx1, ty0, ty1, tz0, tz1;
    tile_range(ix, tx0, tx1); tile_range(iy, ty0, ty1); tile_range(iz, tz0, tz1);
    for (int tz = tz0; tz <= tz1; ++tz)
        for (int ty = ty0; ty <= ty1; ++ty)
            for (int tx = tx0; tx <= tx1; ++tx) {
                int bin = (tz * NTT + ty) * NTT + tx;
                int slot = atomicAdd(&cursor[bin], 1);
                if (slot < cap) {
                    unsigned int pk = ((unsigned int)ray << 12)
                                    | ((unsigned int)(iz - (tz << 3) + 1) << 8)
                                    | ((unsigned int)(iy - (ty << 3) + 1) << 4)
                                    |  (unsigned int)(ix - (tx << 3) + 1);
                    recs[slot] = make_float4(__uint_as_float(pk), fx, fy, fz);
                }
            }
}

// ---------------------------------------------------------------------------
// Pass D: one block (8 z-slab waves) per chunk. Records counting-sorted by
// z-bucket (lz0+1 in [0,8]) in LDS; wave w walks only buckets {w, w+1} --
// exactly the records engaging its z-layer. One 64-lane plain LDS RMW per
// engaged record (4 xy-corners x 16 channels). No atomics in the hot loop.
__global__ __launch_bounds__(ACC_THREADS, 6) void accum_kernel(
    const float* __restrict__ enc,
    const int* __restrict__ offsets, const int* __restrict__ counts,
    const float4* __restrict__ recs, const unsigned int* __restrict__ chunk_info,
    const int* __restrict__ nck,
    float* __restrict__ grid)
{
    if ((int)blockIdx.x >= nck[0]) return;
    unsigned int info = chunk_info[blockIdx.x];
    int bin  = (int)(info & 0xFFFu);
    int k    = (int)((info >> 12) & 0x7FFFFu);
    bool multi = (info & MULTI_FLAG) != 0;
    int cnt  = counts[bin];
    int start = offsets[bin] + k * CHK;
    int n = cnt - k * CHK; if (n > CHK) n = CHK;

    int tx = bin & 15, ty = (bin >> 4) & 15, tz = bin >> 8;
    int gx0 = tx << 3, gy0 = ty << 3, gz0 = tz << 3;

    __shared__ float  tile[TILE_FL];   // 32 KB
    __shared__ float4 srec[CHK];       // 16 KB (z-sorted records)
    __shared__ int zhist[9];
    __shared__ int zbase[10];
    __shared__ int zcur[9];

    int tid = threadIdx.x;
    {
        float4* t4 = (float4*)tile;
        #pragma unroll
        for (int i = tid; i < TILE_FL / 4; i += ACC_THREADS)
            t4[i] = make_float4(0.f, 0.f, 0.f, 0.f);
    }
    if (tid < 9) zhist[tid] = 0;
    __syncthreads();

    // Stage (coalesced) + z-bucket histogram. Each thread handles <=2 records.
    float4 Ra, Rb; int ba = -1, bb = -1;
    if (tid < n) {
        Ra = recs[start + tid];
        ba = (int)((__float_as_uint(Ra.x) >> 8) & 15u);
        atomicAdd(&zhist[ba], 1);
    }
    if (tid + ACC_THREADS < n) {
        Rb = recs[start + tid + ACC_THREADS];
        bb = (int)((__float_as_uint(Rb.x) >> 8) & 15u);
        atomicAdd(&zhist[bb], 1);
    }
    __syncthreads();
    if (tid == 0) {
        int a = 0;
        #pragma unroll
        for (int i = 0; i < 9; ++i) { zbase[i] = a; zcur[i] = a; a += zhist[i]; }
        zbase[9] = a;
    }
    __syncthreads();
    if (ba >= 0) { int p = atomicAdd(&zcur[ba], 1); srec[p] = Ra; }
    if (bb >= 0) { int p = atomicAdd(&zcur[bb], 1); srec[p] = Rb; }
    __syncthreads();

    // Wave w owns z-layer w; engaged records = buckets w (lz0=w-1, cz=1)
    // and w+1 (lz0=w, cz=0).
    int wz   = tid >> 6;
    int lane = tid & 63;
    int c2   = lane >> 4;               // xy-corner 0..3
    int cx   = c2 & 1, cy = c2 >> 1;
    int c    = lane & 15;               // channel

    int r    = zbase[wz];
    int rEnd = zbase[wz + 2];

    // 2-deep pipeline over the wave's engaged range.
    float4 R0 = make_float4(0.f,0.f,0.f,0.f), R1 = R0;
    float ev0 = 0.f, ev1 = 0.f;
    if (r < rEnd) {
        R0 = srec[r];
        ev0 = enc[(__float_as_uint(R0.x) >> 12) * GC + c];
    }
    if (r + 1 < rEnd) {
        R1 = srec[r + 1];
        ev1 = enc[(__float_as_uint(R1.x) >> 12) * GC + c];
    }
    for (; r < rEnd; ++r) {
        float4 Rc = R0; float evc = ev0;
        R0 = R1; ev0 = ev1;
        if (r + 2 < rEnd) {
            R1 = srec[r + 2];
            ev1 = enc[(__float_as_uint(R1.x) >> 12) * GC + c];
        }
        unsigned int pk = __float_as_uint(Rc.x);
        int lx  = (int)(pk & 15u)        - 1 + cx;
        int ly  = (int)((pk >> 4) & 15u) - 1 + cy;
        int lz0 = (int)((pk >> 8) & 15u) - 1;
        float wzv = (wz != lz0) ? Rc.w : 1.0f - Rc.w;   // wave-uniform
        if ((unsigned)lx < 8u && (unsigned)ly < 8u) {
            float wxv = cx ? Rc.y : 1.0f - Rc.y;
            float wyv = cy ? Rc.z : 1.0f - Rc.z;
            tile[((((wz << 3) + ly) << 3) | lx) * GC + c] += wxv * wyv * wzv * evc;
        }
    }
    __syncthreads();

    // Flush: R11's contiguous wave-level pattern (lane-adjacent addresses).
    if (!multi) {
        const float4* t4 = (const float4*)tile;
        for (int i = tid; i < TILE_FL / 4; i += ACC_THREADS) {
            float4 v = t4[i];
            if (v.x == 0.f && v.y == 0.f && v.z == 0.f && v.w == 0.f) continue;
            int point = i >> 2;
            int q = (i & 3) << 2;
            int lx = point & 7, ly = (point >> 3) & 7, lz = point >> 6;
            size_t gf = (((size_t)((gz0 + lz) * GH + gy0 + ly)) * GW + gx0 + lx) * GC + q;
            *(float4*)&grid[gf] = v;
        }
    } else {
        for (int idx = tid; idx < TILE_FL; idx += ACC_THREADS) {
            float v = tile[idx];
            if (v == 0.f) continue;
            int point = idx >> 4, cc = idx & 15;
            int lx = point & 7, ly = (point >> 3) & 7, lz = point >> 6;
            unsafeAtomicAdd(
                &grid[(((gz0 + lz) * GH + gy0 + ly) * GW + gx0 + lx) * GC + cc], v);
        }
    }
}

// ---------------------------------------------------------------------------
// Fallback: direct atomic splat (round-1 kernel) if d_ws is too small.
__global__ __launch_bounds__(256) void splat_direct(
    const float* __restrict__ dirs, const float* __restrict__ orig,
    const float* __restrict__ nearv, const float* __restrict__ farv,
    const float* __restrict__ enc,
    float* __restrict__ grid, int n_rays)
{
    int gt = blockIdx.x * blockDim.x + threadIdx.x;
    int group = gt >> 4;
    int c = gt & 15;
    if (group >= n_rays * ST) return;
    int ray = group / ST;
    int s   = group - ray * ST;
    int ix, iy, iz; float fx, fy, fz;
    if (!compute_sample(dirs, orig, nearv, farv, ray, s, ix, iy, iz, fx, fy, fz))
        return;
    float ev = enc[ray * GC + c];
    float gx0 = 1.0f - fx, gy0 = 1.0f - fy, gz0 = 1.0f - fz;
    #pragma unroll
    for (int corner = 0; corner < 8; ++corner) {
        int cx = corner & 1, cy = (corner >> 1) & 1, cz = (corner >> 2) & 1;
        int jx = ix + cx, jy = iy + cy, jz = iz + cz;
        if (jx < 0 || jx >= GW || jy < 0 || jy >= GH || jz < 0 || jz >= GD) continue;
        float w = (cx ? fx : gx0) * (cy ? fy : gy0) * (cz ? fz : gz0);
        unsafeAtomicAdd(&grid[((jz * GH + jy) * GW + jx) * GC + c], w * ev);
    }
}

// ---------------------------------------------------------------------------
extern "C" void kernel_launch(void* const* d_in, const int* in_sizes, int n_in,
                              void* d_out, int out_size, void* d_ws, size_t ws_size,
                              hipStream_t stream) {
    const float* dirs  = (const float*)d_in[0];
    const float* orig  = (const float*)d_in[1];
    const float* nearv = (const float*)d_in[2];
    const float* farv  = (const float*)d_in[3];
    const float* enc   = (const float*)d_in[4];
    float* out = (float*)d_out;

    int n_rays = in_sizes[2];
    int total  = n_rays * ST;

    hipMemsetAsync(out, 0, (size_t)out_size * sizeof(float), stream);

    // Workspace layout: [counts|offsets|cursor|nck|chunk_info| (align16) recs]
    int cap = total + total / 2;                 // record capacity (~1.5x)
    int maxck = NBINS + cap / CHK + 2;           // chunk-table bound
    size_t prefix_ints = (size_t)NBINS * 3 + 1 + (size_t)maxck;
    prefix_ints = (prefix_ints + 3) & ~(size_t)3;        // align recs to 16 B
    size_t need = prefix_ints * 4 + (size_t)cap * 16;

    if (ws_size < need || n_rays >= (1 << 20)) {
        long long tthreads = (long long)total * 16;
        int blocks = (int)((tthreads + 255) / 256);
        splat_direct<<<blocks, 256, 0, stream>>>(dirs, orig, nearv, farv, enc,
                                                 out, n_rays);
        return;
    }

    int* counts  = (int*)d_ws;
    int* offsets = counts + NBINS;
    int* cursor  = offsets + NBINS;
    int* nck     = cursor + NBINS;
    unsigned int* chunk_info = (unsigned int*)(nck + 1);
    float4* recs = (float4*)((int*)d_ws + prefix_ints);

    hipMemsetAsync(counts, 0, NBINS * sizeof(int), stream);
    count_kernel<<<1024, 256, 0, stream>>>(dirs, orig, nearv, farv, counts, total);
    scan_kernel<<<1, 256, 0, stream>>>(counts, offsets, cursor, chunk_info, nck);
    scatter_kernel<<<(total + 255) / 256, 256, 0, stream>>>(
        dirs, orig, nearv, farv, cursor, recs, total, cap);
    accum_kernel<<<maxck, ACC_THREADS, 0, stream>>>(
        enc, offsets, counts, recs, chunk_info, nck, out);
}

// Round 14
// 280.811 us; speedup vs baseline: 2.7904x; 1.4396x over previous
//
#include <hip/hip_runtime.h>

// LightplaneSplatter: trilinear scatter-splat of per-ray encodings (C=16)
// into a (1,128,128,128,16) fp32 grid.
//
// Round 14: wave-run aggregated scatter.
//   R13: accum fixed (182us, VALU 81%); scatter now co-bottleneck at 181us
//   with WRITE=59.5MB = records x 64B (every 16B record its own line) and
//   per-sample cursor atomics serializing on hot bins. Fix: consecutive
//   lanes = consecutive samples of a ray -> same-bin runs; detect runs via
//   shfl_up, leader does ONE atomicAdd(cursor,runLen), broadcasts base,
//   lanes write contiguous slots (wave-coalesced lines). count/scan/accum
//   byte-identical to R13.

#define NS   64
#define NSI  8
#define ST   (NS + NSI)   // 72
#define GD   128
#define GH   128
#define GW   128
#define GC   16
#define DISP_INF 1e-4f

#define NTT   16                    // tiles per axis (8 points each)
#define NBINS (NTT * NTT * NTT)     // 4096
#define TILE_FL (8 * 8 * 8 * GC)    // 8192 floats = 32 KB
#define CHK   1024                  // samples per chunk
#define MULTI_FLAG 0x80000000u
#define ACC_THREADS 512             // 8 waves, one z-layer each

// ---------------------------------------------------------------------------
__device__ __forceinline__ bool compute_sample(
    const float* __restrict__ dirs, const float* __restrict__ orig,
    const float* __restrict__ nearv, const float* __restrict__ farv,
    int ray, int s,
    int& ix, int& iy, int& iz, float& fx, float& fy, float& fz)
{
    float nr = nearv[ray], fr = farv[ray];
    float t;
    if (s < NS) {
        float frac = ((float)s + 0.5f) * (1.0f / (float)NS);
        t = nr + (fr - nr) * frac;
    } else {
        float j    = (float)(s - NS + 1) * (1.0f / (float)NSI);
        float invf = 1.0f / fr;
        float disp = invf + (DISP_INF - invf) * j;
        t = 1.0f / disp;
    }
    float px = orig[ray*3+0] + t * dirs[ray*3+0];
    float py = orig[ray*3+1] + t * dirs[ray*3+1];
    float pz = orig[ray*3+2] + t * dirs[ray*3+2];
    float vx = (px + 1.0f) * 0.5f * 127.0f;
    float vy = (py + 1.0f) * 0.5f * 127.0f;
    float vz = (pz + 1.0f) * 0.5f * 127.0f;
    float bx = floorf(vx), by = floorf(vy), bz = floorf(vz);
    fx = vx - bx; fy = vy - by; fz = vz - bz;
    ix = (int)bx; iy = (int)by; iz = (int)bz;
    return !(ix < -1 || ix > GW - 1 ||
             iy < -1 || iy > GH - 1 ||
             iz < -1 || iz > GD - 1);
}

// Tile range touched by base cell i along one axis (i in [-1, 127]).
__device__ __forceinline__ void tile_range(int i, int& t0, int& t1)
{
    t0 = (i < 0 ? 0 : i) >> 3;
    t1 = (i + 1 > 127 ? 127 : i + 1) >> 3;
}

// ---------------------------------------------------------------------------
// Pass A: per-tile sample counts (with duplication for boundary footprints).
__global__ __launch_bounds__(256) void count_kernel(
    const float* __restrict__ dirs, const float* __restrict__ orig,
    const float* __restrict__ nearv, const float* __restrict__ farv,
    int* __restrict__ counts, int total)
{
    __shared__ int h[NBINS];
    for (int i = threadIdx.x; i < NBINS; i += 256) h[i] = 0;
    __syncthreads();
    for (int idx = blockIdx.x * 256 + threadIdx.x; idx < total;
         idx += gridDim.x * 256) {
        int ray = idx / ST, s = idx - (idx / ST) * ST;
        int ix, iy, iz; float fx, fy, fz;
        if (!compute_sample(dirs, orig, nearv, farv, ray, s, ix, iy, iz, fx, fy, fz))
            continue;
        int tx0, tx1, ty0, ty1, tz0, tz1;
        tile_range(ix, tx0, tx1); tile_range(iy, ty0, ty1); tile_range(iz, tz0, tz1);
        for (int tz = tz0; tz <= tz1; ++tz)
            for (int ty = ty0; ty <= ty1; ++ty)
                for (int tx = tx0; tx <= tx1; ++tx)
                    atomicAdd(&h[(tz * NTT + ty) * NTT + tx], 1);
    }
    __syncthreads();
    for (int i = threadIdx.x; i < NBINS; i += 256)
        if (h[i]) atomicAdd(&counts[i], h[i]);
}

// ---------------------------------------------------------------------------
// Pass B: scan counts -> offsets/cursor; emit chunk table.
__global__ __launch_bounds__(256) void scan_kernel(
    const int* __restrict__ counts, int* __restrict__ offsets,
    int* __restrict__ cursor, unsigned int* __restrict__ chunk_info,
    int* __restrict__ nck)
{
    __shared__ int p1[256], p2[256];
    const int CH = NBINS / 256;  // 16
    int tid = threadIdx.x;
    int base = tid * CH;
    int s1 = 0, s2 = 0;
    for (int i = 0; i < CH; ++i) {
        int c = counts[base + i];
        s1 += c;
        s2 += (c + CHK - 1) / CHK;
    }
    p1[tid] = s1; p2[tid] = s2;
    __syncthreads();
    if (tid == 0) {
        int a1 = 0, a2 = 0;
        for (int i = 0; i < 256; ++i) {
            int v1 = p1[i], v2 = p2[i];
            p1[i] = a1; p2[i] = a2;
            a1 += v1; a2 += v2;
        }
        nck[0] = a2;
    }
    __syncthreads();
    int run = p1[tid];
    int crun = p2[tid];
    for (int i = 0; i < CH; ++i) {
        int bin = base + i;
        int c = counts[bin];
        offsets[bin] = run;
        cursor[bin]  = run;
        int nc = (c + CHK - 1) / CHK;
        unsigned int mf = (nc > 1) ? MULTI_FLAG : 0u;
        for (int k = 0; k < nc; ++k)
            chunk_info[crun + k] = (unsigned int)bin | ((unsigned int)k << 12) | mf;
        crun += nc;
        run += c;
    }
}

// ---------------------------------------------------------------------------
// Pass C: scatter fat records into per-tile lists, wave-run aggregated.
// Record: float4 { uint pack = ray<<12 | (lz0+1)<<8 | (ly0+1)<<4 | (lx0+1),
//                  fx, fy, fz }  with l*0 = base cell relative to tile origin.
__global__ __launch_bounds__(256) void scatter_kernel(
    const float* __restrict__ dirs, const float* __restrict__ orig,
    const float* __restrict__ nearv, const float* __restrict__ farv,
    int* __restrict__ cursor, float4* __restrict__ recs, int total, int cap)
{
    int idx  = blockIdx.x * 256 + threadIdx.x;
    int lane = threadIdx.x & 63;
    bool act = (idx < total);

    int ix = 0, iy = 0, iz = 0; float fx = 0.f, fy = 0.f, fz = 0.f;
    int tx0 = 0, tx1 = -1, ty0 = 0, ty1 = -1, tz0 = 0, tz1 = -1;
    int ray = 0;
    if (act) {
        ray = idx / ST;
        int s = idx - ray * ST;
        if (compute_sample(dirs, orig, nearv, farv, ray, s, ix, iy, iz, fx, fy, fz)) {
            tile_range(ix, tx0, tx1);
            tile_range(iy, ty0, ty1);
            tile_range(iz, tz0, tz1);
        }
    }

    // Up to 8 footprint copies; same copy-index k across the wave so that
    // neighboring lanes (consecutive samples of a ray) form same-bin runs.
    #pragma unroll
    for (int kz = 0; kz < 2; ++kz)
    #pragma unroll
    for (int ky = 0; ky < 2; ++ky)
    #pragma unroll
    for (int kx = 0; kx < 2; ++kx) {
        int tzi = tz0 + kz, tyi = ty0 + ky, txi = tx0 + kx;
        int bin = (tzi <= tz1 && tyi <= ty1 && txi <= tx1)
                ? (tzi * NTT + tyi) * NTT + txi : -1;

        // Run detection: leader = first lane of a maximal same-bin run.
        int prev = __shfl_up(bin, 1, 64);
        bool leader = (lane == 0) || (bin != prev);
        unsigned long long lm = __ballot(leader);

        // My leader = highest set bit <= lane. (2ull<<63)-1 wraps to ~0ull.
        unsigned long long below = lm & ((2ull << lane) - 1ull);
        int lead = 63 - __clzll(below);

        int base = 0;
        if (leader && bin >= 0) {
            unsigned long long rest = (lane == 63) ? 0ull : (lm >> (lane + 1));
            int next = rest ? (lane + 1 + (__ffsll((long long)rest) - 1)) : 64;
            base = atomicAdd(&cursor[bin], next - lane);
        }
        base = __shfl(base, lead, 64);

        if (bin >= 0) {
            int slot = base + (lane - lead);
            if (slot < cap) {
                unsigned int pk = ((unsigned int)ray << 12)
                                | ((unsigned int)(iz - (tzi << 3) + 1) << 8)
                                | ((unsigned int)(iy - (tyi << 3) + 1) << 4)
                                |  (unsigned int)(ix - (txi << 3) + 1);
                recs[slot] = make_float4(__uint_as_float(pk), fx, fy, fz);
            }
        }
    }
}

// ---------------------------------------------------------------------------
// Pass D: one block (8 z-slab waves) per chunk. Records counting-sorted by
// z-bucket (lz0+1 in [0,8]) in LDS; wave w walks only buckets {w, w+1} --
// exactly the records engaging its z-layer. One 64-lane plain LDS RMW per
// engaged record (4 xy-corners x 16 channels). No atomics in the hot loop.
__global__ __launch_bounds__(ACC_THREADS, 6) void accum_kernel(
    const float* __restrict__ enc,
    const int* __restrict__ offsets, const int* __restrict__ counts,
    const float4* __restrict__ recs, const unsigned int* __restrict__ chunk_info,
    const int* __restrict__ nck,
    float* __restrict__ grid)
{
    if ((int)blockIdx.x >= nck[0]) return;
    unsigned int info = chunk_info[blockIdx.x];
    int bin  = (int)(info & 0xFFFu);
    int k    = (int)((info >> 12) & 0x7FFFFu);
    bool multi = (info & MULTI_FLAG) != 0;
    int cnt  = counts[bin];
    int start = offsets[bin] + k * CHK;
    int n = cnt - k * CHK; if (n > CHK) n = CHK;

    int tx = bin & 15, ty = (bin >> 4) & 15, tz = bin >> 8;
    int gx0 = tx << 3, gy0 = ty << 3, gz0 = tz << 3;

    __shared__ float  tile[TILE_FL];   // 32 KB
    __shared__ float4 srec[CHK];       // 16 KB (z-sorted records)
    __shared__ int zhist[9];
    __shared__ int zbase[10];
    __shared__ int zcur[9];

    int tid = threadIdx.x;
    {
        float4* t4 = (float4*)tile;
        #pragma unroll
        for (int i = tid; i < TILE_FL / 4; i += ACC_THREADS)
            t4[i] = make_float4(0.f, 0.f, 0.f, 0.f);
    }
    if (tid < 9) zhist[tid] = 0;
    __syncthreads();

    // Stage (coalesced) + z-bucket histogram. Each thread handles <=2 records.
    float4 Ra, Rb; int ba = -1, bb = -1;
    if (tid < n) {
        Ra = recs[start + tid];
        ba = (int)((__float_as_uint(Ra.x) >> 8) & 15u);
        atomicAdd(&zhist[ba], 1);
    }
    if (tid + ACC_THREADS < n) {
        Rb = recs[start + tid + ACC_THREADS];
        bb = (int)((__float_as_uint(Rb.x) >> 8) & 15u);
        atomicAdd(&zhist[bb], 1);
    }
    __syncthreads();
    if (tid == 0) {
        int a = 0;
        #pragma unroll
        for (int i = 0; i < 9; ++i) { zbase[i] = a; zcur[i] = a; a += zhist[i]; }
        zbase[9] = a;
    }
    __syncthreads();
    if (ba >= 0) { int p = atomicAdd(&zcur[ba], 1); srec[p] = Ra; }
    if (bb >= 0) { int p = atomicAdd(&zcur[bb], 1); srec[p] = Rb; }
    __syncthreads();

    // Wave w owns z-layer w; engaged records = buckets w (lz0=w-1, cz=1)
    // and w+1 (lz0=w, cz=0).
    int wz   = tid >> 6;
    int lane = tid & 63;
    int c2   = lane >> 4;               // xy-corner 0..3
    int cx   = c2 & 1, cy = c2 >> 1;
    int c    = lane & 15;               // channel

    int r    = zbase[wz];
    int rEnd = zbase[wz + 2];

    // 2-deep pipeline over the wave's engaged range.
    float4 R0 = make_float4(0.f,0.f,0.f,0.f), R1 = R0;
    float ev0 = 0.f, ev1 = 0.f;
    if (r < rEnd) {
        R0 = srec[r];
        ev0 = enc[(__float_as_uint(R0.x) >> 12) * GC + c];
    }
    if (r + 1 < rEnd) {
        R1 = srec[r + 1];
        ev1 = enc[(__float_as_uint(R1.x) >> 12) * GC + c];
    }
    for (; r < rEnd; ++r) {
        float4 Rc = R0; float evc = ev0;
        R0 = R1; ev0 = ev1;
        if (r + 2 < rEnd) {
            R1 = srec[r + 2];
            ev1 = enc[(__float_as_uint(R1.x) >> 12) * GC + c];
        }
        unsigned int pk = __float_as_uint(Rc.x);
        int lx  = (int)(pk & 15u)        - 1 + cx;
        int ly  = (int)((pk >> 4) & 15u) - 1 + cy;
        int lz0 = (int)((pk >> 8) & 15u) - 1;
        float wzv = (wz != lz0) ? Rc.w : 1.0f - Rc.w;   // wave-uniform
        if ((unsigned)lx < 8u && (unsigned)ly < 8u) {
            float wxv = cx ? Rc.y : 1.0f - Rc.y;
            float wyv = cy ? Rc.z : 1.0f - Rc.z;
            tile[((((wz << 3) + ly) << 3) | lx) * GC + c] += wxv * wyv * wzv * evc;
        }
    }
    __syncthreads();

    // Flush: contiguous wave-level pattern (lane-adjacent addresses).
    if (!multi) {
        const float4* t4 = (const float4*)tile;
        for (int i = tid; i < TILE_FL / 4; i += ACC_THREADS) {
            float4 v = t4[i];
            if (v.x == 0.f && v.y == 0.f && v.z == 0.f && v.w == 0.f) continue;
            int point = i >> 2;
            int q = (i & 3) << 2;
            int lx = point & 7, ly = (point >> 3) & 7, lz = point >> 6;
            size_t gf = (((size_t)((gz0 + lz) * GH + gy0 + ly)) * GW + gx0 + lx) * GC + q;
            *(float4*)&grid[gf] = v;
        }
    } else {
        for (int idx = tid; idx < TILE_FL; idx += ACC_THREADS) {
            float v = tile[idx];
            if (v == 0.f) continue;
            int point = idx >> 4, cc = idx & 15;
            int lx = point & 7, ly = (point >> 3) & 7, lz = point >> 6;
            unsafeAtomicAdd(
                &grid[(((gz0 + lz) * GH + gy0 + ly) * GW + gx0 + lx) * GC + cc], v);
        }
    }
}

// ---------------------------------------------------------------------------
// Fallback: direct atomic splat (round-1 kernel) if d_ws is too small.
__global__ __launch_bounds__(256) void splat_direct(
    const float* __restrict__ dirs, const float* __restrict__ orig,
    const float* __restrict__ nearv, const float* __restrict__ farv,
    const float* __restrict__ enc,
    float* __restrict__ grid, int n_rays)
{
    int gt = blockIdx.x * blockDim.x + threadIdx.x;
    int group = gt >> 4;
    int c = gt & 15;
    if (group >= n_rays * ST) return;
    int ray = group / ST;
    int s   = group - ray * ST;
    int ix, iy, iz; float fx, fy, fz;
    if (!compute_sample(dirs, orig, nearv, farv, ray, s, ix, iy, iz, fx, fy, fz))
        return;
    float ev = enc[ray * GC + c];
    float gx0 = 1.0f - fx, gy0 = 1.0f - fy, gz0 = 1.0f - fz;
    #pragma unroll
    for (int corner = 0; corner < 8; ++corner) {
        int cx = corner & 1, cy = (corner >> 1) & 1, cz = (corner >> 2) & 1;
        int jx = ix + cx, jy = iy + cy, jz = iz + cz;
        if (jx < 0 || jx >= GW || jy < 0 || jy >= GH || jz < 0 || jz >= GD) continue;
        float w = (cx ? fx : gx0) * (cy ? fy : gy0) * (cz ? fz : gz0);
        unsafeAtomicAdd(&grid[((jz * GH + jy) * GW + jx) * GC + c], w * ev);
    }
}

// ---------------------------------------------------------------------------
extern "C" void kernel_launch(void* const* d_in, const int* in_sizes, int n_in,
                              void* d_out, int out_size, void* d_ws, size_t ws_size,
                              hipStream_t stream) {
    const float* dirs  = (const float*)d_in[0];
    const float* orig  = (const float*)d_in[1];
    const float* nearv = (const float*)d_in[2];
    const float* farv  = (const float*)d_in[3];
    const float* enc   = (const float*)d_in[4];
    float* out = (float*)d_out;

    int n_rays = in_sizes[2];
    int total  = n_rays * ST;

    hipMemsetAsync(out, 0, (size_t)out_size * sizeof(float), stream);

    // Workspace layout: [counts|offsets|cursor|nck|chunk_info| (align16) recs]
    int cap = total + total / 2;                 // record capacity (~1.5x)
    int maxck = NBINS + cap / CHK + 2;           // chunk-table bound
    size_t prefix_ints = (size_t)NBINS * 3 + 1 + (size_t)maxck;
    prefix_ints = (prefix_ints + 3) & ~(size_t)3;        // align recs to 16 B
    size_t need = prefix_ints * 4 + (size_t)cap * 16;

    if (ws_size < need || n_rays >= (1 << 20)) {
        long long tthreads = (long long)total * 16;
        int blocks = (int)((tthreads + 255) / 256);
        splat_direct<<<blocks, 256, 0, stream>>>(dirs, orig, nearv, farv, enc,
                                                 out, n_rays);
        return;
    }

    int* counts  = (int*)d_ws;
    int* offsets = counts + NBINS;
    int* cursor  = offsets + NBINS;
    int* nck     = cursor + NBINS;
    unsigned int* chunk_info = (unsigned int*)(nck + 1);
    float4* recs = (float4*)((int*)d_ws + prefix_ints);

    hipMemsetAsync(counts, 0, NBINS * sizeof(int), stream);
    count_kernel<<<1024, 256, 0, stream>>>(dirs, orig, nearv, farv, counts, total);
    scan_kernel<<<1, 256, 0, stream>>>(counts, offsets, cursor, chunk_info, nck);
    scatter_kernel<<<(total + 255) / 256, 256, 0, stream>>>(
        dirs, orig, nearv, farv, cursor, recs, total, cap);
    accum_kernel<<<maxck, ACC_THREADS, 0, stream>>>(
        enc, offsets, counts, recs, chunk_info, nck, out);
}

// Round 15
// 258.981 us; speedup vs baseline: 3.0256x; 1.0843x over previous
//
#include <hip/hip_runtime.h>

// LightplaneSplatter: trilinear scatter-splat of per-ray encodings (C=16)
// into a (1,128,128,128,16) fp32 grid.
//
// Round 15: accum inner-loop instruction diet (accum-only change).
//   R14: accum is the sole bottleneck, VALU-issue-bound (81-84% VALUBusy,
//   ~28 VALU/record-wave-op). Diet: (1) split bucket-pair walk into two
//   loops with compile-time z-weight (no per-record z test), (2) scalarize
//   wave-uniform loop bounds + enc base via readfirstlane, (3) sentinel-
//   clamped prefetch (no per-iter branches), (4) fused (lx|ly)<8 bounds
//   test, (5) re-associated weight product. count/scan/scatter/flush
//   byte-identical to R14.

#define NS   64
#define NSI  8
#define ST   (NS + NSI)   // 72
#define GD   128
#define GH   128
#define GW   128
#define GC   16
#define DISP_INF 1e-4f

#define NTT   16                    // tiles per axis (8 points each)
#define NBINS (NTT * NTT * NTT)     // 4096
#define TILE_FL (8 * 8 * 8 * GC)    // 8192 floats = 32 KB
#define CHK   1024                  // samples per chunk
#define MULTI_FLAG 0x80000000u
#define ACC_THREADS 512             // 8 waves, one z-layer each

// ---------------------------------------------------------------------------
__device__ __forceinline__ bool compute_sample(
    const float* __restrict__ dirs, const float* __restrict__ orig,
    const float* __restrict__ nearv, const float* __restrict__ farv,
    int ray, int s,
    int& ix, int& iy, int& iz, float& fx, float& fy, float& fz)
{
    float nr = nearv[ray], fr = farv[ray];
    float t;
    if (s < NS) {
        float frac = ((float)s + 0.5f) * (1.0f / (float)NS);
        t = nr + (fr - nr) * frac;
    } else {
        float j    = (float)(s - NS + 1) * (1.0f / (float)NSI);
        float invf = 1.0f / fr;
        float disp = invf + (DISP_INF - invf) * j;
        t = 1.0f / disp;
    }
    float px = orig[ray*3+0] + t * dirs[ray*3+0];
    float py = orig[ray*3+1] + t * dirs[ray*3+1];
    float pz = orig[ray*3+2] + t * dirs[ray*3+2];
    float vx = (px + 1.0f) * 0.5f * 127.0f;
    float vy = (py + 1.0f) * 0.5f * 127.0f;
    float vz = (pz + 1.0f) * 0.5f * 127.0f;
    float bx = floorf(vx), by = floorf(vy), bz = floorf(vz);
    fx = vx - bx; fy = vy - by; fz = vz - bz;
    ix = (int)bx; iy = (int)by; iz = (int)bz;
    return !(ix < -1 || ix > GW - 1 ||
             iy < -1 || iy > GH - 1 ||
             iz < -1 || iz > GD - 1);
}

// Tile range touched by base cell i along one axis (i in [-1, 127]).
__device__ __forceinline__ void tile_range(int i, int& t0, int& t1)
{
    t0 = (i < 0 ? 0 : i) >> 3;
    t1 = (i + 1 > 127 ? 127 : i + 1) >> 3;
}

// ---------------------------------------------------------------------------
// Pass A: per-tile sample counts (with duplication for boundary footprints).
__global__ __launch_bounds__(256) void count_kernel(
    const float* __restrict__ dirs, const float* __restrict__ orig,
    const float* __restrict__ nearv, const float* __restrict__ farv,
    int* __restrict__ counts, int total)
{
    __shared__ int h[NBINS];
    for (int i = threadIdx.x; i < NBINS; i += 256) h[i] = 0;
    __syncthreads();
    for (int idx = blockIdx.x * 256 + threadIdx.x; idx < total;
         idx += gridDim.x * 256) {
        int ray = idx / ST, s = idx - (idx / ST) * ST;
        int ix, iy, iz; float fx, fy, fz;
        if (!compute_sample(dirs, orig, nearv, farv, ray, s, ix, iy, iz, fx, fy, fz))
            continue;
        int tx0, tx1, ty0, ty1, tz0, tz1;
        tile_range(ix, tx0, tx1); tile_range(iy, ty0, ty1); tile_range(iz, tz0, tz1);
        for (int tz = tz0; tz <= tz1; ++tz)
            for (int ty = ty0; ty <= ty1; ++ty)
                for (int tx = tx0; tx <= tx1; ++tx)
                    atomicAdd(&h[(tz * NTT + ty) * NTT + tx], 1);
    }
    __syncthreads();
    for (int i = threadIdx.x; i < NBINS; i += 256)
        if (h[i]) atomicAdd(&counts[i], h[i]);
}

// ---------------------------------------------------------------------------
// Pass B: scan counts -> offsets/cursor; emit chunk table.
__global__ __launch_bounds__(256) void scan_kernel(
    const int* __restrict__ counts, int* __restrict__ offsets,
    int* __restrict__ cursor, unsigned int* __restrict__ chunk_info,
    int* __restrict__ nck)
{
    __shared__ int p1[256], p2[256];
    const int CH = NBINS / 256;  // 16
    int tid = threadIdx.x;
    int base = tid * CH;
    int s1 = 0, s2 = 0;
    for (int i = 0; i < CH; ++i) {
        int c = counts[base + i];
        s1 += c;
        s2 += (c + CHK - 1) / CHK;
    }
    p1[tid] = s1; p2[tid] = s2;
    __syncthreads();
    if (tid == 0) {
        int a1 = 0, a2 = 0;
        for (int i = 0; i < 256; ++i) {
            int v1 = p1[i], v2 = p2[i];
            p1[i] = a1; p2[i] = a2;
            a1 += v1; a2 += v2;
        }
        nck[0] = a2;
    }
    __syncthreads();
    int run = p1[tid];
    int crun = p2[tid];
    for (int i = 0; i < CH; ++i) {
        int bin = base + i;
        int c = counts[bin];
        offsets[bin] = run;
        cursor[bin]  = run;
        int nc = (c + CHK - 1) / CHK;
        unsigned int mf = (nc > 1) ? MULTI_FLAG : 0u;
        for (int k = 0; k < nc; ++k)
            chunk_info[crun + k] = (unsigned int)bin | ((unsigned int)k << 12) | mf;
        crun += nc;
        run += c;
    }
}

// ---------------------------------------------------------------------------
// Pass C: scatter fat records into per-tile lists, wave-run aggregated.
// Record: float4 { uint pack = ray<<12 | (lz0+1)<<8 | (ly0+1)<<4 | (lx0+1),
//                  fx, fy, fz }  with l*0 = base cell relative to tile origin.
__global__ __launch_bounds__(256) void scatter_kernel(
    const float* __restrict__ dirs, const float* __restrict__ orig,
    const float* __restrict__ nearv, const float* __restrict__ farv,
    int* __restrict__ cursor, float4* __restrict__ recs, int total, int cap)
{
    int idx  = blockIdx.x * 256 + threadIdx.x;
    int lane = threadIdx.x & 63;
    bool act = (idx < total);

    int ix = 0, iy = 0, iz = 0; float fx = 0.f, fy = 0.f, fz = 0.f;
    int tx0 = 0, tx1 = -1, ty0 = 0, ty1 = -1, tz0 = 0, tz1 = -1;
    int ray = 0;
    if (act) {
        ray = idx / ST;
        int s = idx - ray * ST;
        if (compute_sample(dirs, orig, nearv, farv, ray, s, ix, iy, iz, fx, fy, fz)) {
            tile_range(ix, tx0, tx1);
            tile_range(iy, ty0, ty1);
            tile_range(iz, tz0, tz1);
        }
    }

    // Up to 8 footprint copies; same copy-index k across the wave so that
    // neighboring lanes (consecutive samples of a ray) form same-bin runs.
    #pragma unroll
    for (int kz = 0; kz < 2; ++kz)
    #pragma unroll
    for (int ky = 0; ky < 2; ++ky)
    #pragma unroll
    for (int kx = 0; kx < 2; ++kx) {
        int tzi = tz0 + kz, tyi = ty0 + ky, txi = tx0 + kx;
        int bin = (tzi <= tz1 && tyi <= ty1 && txi <= tx1)
                ? (tzi * NTT + tyi) * NTT + txi : -1;

        // Run detection: leader = first lane of a maximal same-bin run.
        int prev = __shfl_up(bin, 1, 64);
        bool leader = (lane == 0) || (bin != prev);
        unsigned long long lm = __ballot(leader);

        // My leader = highest set bit <= lane. (2ull<<63)-1 wraps to ~0ull.
        unsigned long long below = lm & ((2ull << lane) - 1ull);
        int lead = 63 - __clzll(below);

        int base = 0;
        if (leader && bin >= 0) {
            unsigned long long rest = (lane == 63) ? 0ull : (lm >> (lane + 1));
            int next = rest ? (lane + 1 + (__ffsll((long long)rest) - 1)) : 64;
            base = atomicAdd(&cursor[bin], next - lane);
        }
        base = __shfl(base, lead, 64);

        if (bin >= 0) {
            int slot = base + (lane - lead);
            if (slot < cap) {
                unsigned int pk = ((unsigned int)ray << 12)
                                | ((unsigned int)(iz - (tzi << 3) + 1) << 8)
                                | ((unsigned int)(iy - (tyi << 3) + 1) << 4)
                                |  (unsigned int)(ix - (txi << 3) + 1);
                recs[slot] = make_float4(__uint_as_float(pk), fx, fy, fz);
            }
        }
    }
}

// ---------------------------------------------------------------------------
// Pass D: one block (8 z-slab waves) per chunk. Records counting-sorted by
// z-bucket (lz0+1 in [0,8]) in LDS; wave w walks buckets w (cz=1) and w+1
// (cz=0) in two separate loops with compile-time z-weight. One 64-lane plain
// LDS RMW per engaged record (4 xy-corners x 16 channels). No hot-loop
// atomics; loop control scalarized; sentinel-clamped 2-deep prefetch.
__global__ __launch_bounds__(ACC_THREADS, 6) void accum_kernel(
    const float* __restrict__ enc,
    const int* __restrict__ offsets, const int* __restrict__ counts,
    const float4* __restrict__ recs, const unsigned int* __restrict__ chunk_info,
    const int* __restrict__ nck,
    float* __restrict__ grid)
{
    if ((int)blockIdx.x >= nck[0]) return;
    unsigned int info = chunk_info[blockIdx.x];
    int bin  = (int)(info & 0xFFFu);
    int k    = (int)((info >> 12) & 0x7FFFFu);
    bool multi = (info & MULTI_FLAG) != 0;
    int cnt  = counts[bin];
    int start = offsets[bin] + k * CHK;
    int n = cnt - k * CHK; if (n > CHK) n = CHK;

    int tx = bin & 15, ty = (bin >> 4) & 15, tz = bin >> 8;
    int gx0 = tx << 3, gy0 = ty << 3, gz0 = tz << 3;

    __shared__ float  tile[TILE_FL];   // 32 KB
    __shared__ float4 srec[CHK];       // 16 KB (z-sorted records)
    __shared__ int zhist[9];
    __shared__ int zbase[10];
    __shared__ int zcur[9];

    int tid = threadIdx.x;
    {
        float4* t4 = (float4*)tile;
        #pragma unroll
        for (int i = tid; i < TILE_FL / 4; i += ACC_THREADS)
            t4[i] = make_float4(0.f, 0.f, 0.f, 0.f);
    }
    if (tid < 9) zhist[tid] = 0;
    __syncthreads();

    // Stage (coalesced) + z-bucket histogram. Each thread handles <=2 records.
    float4 Ra, Rb; int ba = -1, bb = -1;
    if (tid < n) {
        Ra = recs[start + tid];
        ba = (int)((__float_as_uint(Ra.x) >> 8) & 15u);
        atomicAdd(&zhist[ba], 1);
    }
    if (tid + ACC_THREADS < n) {
        Rb = recs[start + tid + ACC_THREADS];
        bb = (int)((__float_as_uint(Rb.x) >> 8) & 15u);
        atomicAdd(&zhist[bb], 1);
    }
    __syncthreads();
    if (tid == 0) {
        int a = 0;
        #pragma unroll
        for (int i = 0; i < 9; ++i) { zbase[i] = a; zcur[i] = a; a += zhist[i]; }
        zbase[9] = a;
    }
    __syncthreads();
    if (ba >= 0) { int p = atomicAdd(&zcur[ba], 1); srec[p] = Ra; }
    if (bb >= 0) { int p = atomicAdd(&zcur[bb], 1); srec[p] = Rb; }
    __syncthreads();

    // Wave w owns z-layer w. Bucket w: lz0 = w-1, cz=1 (wzv = fz).
    // Bucket w+1: lz0 = w, cz=0 (wzv = 1-fz).
    int swz  = __builtin_amdgcn_readfirstlane(tid >> 6);
    int lane = tid & 63;
    int c2   = lane >> 4;               // xy-corner 0..3
    int cx   = c2 & 1, cy = c2 >> 1;
    int c    = lane & 15;               // channel
    int dxm1 = cx - 1, dym1 = cy - 1;   // per-lane decode offsets
    int wzofs = swz << 6;               // wz * 64 points (scalar)

    int rA = __builtin_amdgcn_readfirstlane(zbase[swz]);
    int rM = __builtin_amdgcn_readfirstlane(zbase[swz + 1]);
    int rB = __builtin_amdgcn_readfirstlane(zbase[swz + 2]);

    // Process record Rc with z-weight formula fixed at compile time.
#define PROC(Rc, evc, CZ1) do {                                              \
        unsigned int pk_ = __float_as_uint((Rc).x);                          \
        int lx_ = (int)(pk_ & 15u) + dxm1;                                   \
        int ly_ = (int)((pk_ >> 4) & 15u) + dym1;                            \
        if ((unsigned)(lx_ | ly_) < 8u) {                                    \
            float wx_ = cx ? (Rc).y : 1.0f - (Rc).y;                         \
            float wy_ = cy ? (Rc).z : 1.0f - (Rc).z;                         \
            float wz_ = (CZ1) ? (Rc).w : 1.0f - (Rc).w;                      \
            int off_ = ((wzofs + (ly_ << 3) + lx_) << 4) + c;                \
            tile[off_] += (wx_ * wy_) * (wz_ * evc);                         \
        }                                                                    \
    } while (0)

    // 2-deep pipelined walk of [lo,hi) with sentinel-clamped prefetch.
#define RUNRANGE(lo, hi, CZ1) do {                                           \
        int r_ = (lo);                                                       \
        if (r_ < (hi)) {                                                     \
            int last_ = (hi) - 1;                                            \
            float4 R0_ = srec[r_];                                           \
            unsigned sp0_ = __builtin_amdgcn_readfirstlane(                  \
                                __float_as_uint(R0_.x));                     \
            float e0_ = (enc + ((sp0_ >> 12) << 4))[c];                      \
            int rn_ = r_ + 1 < last_ ? r_ + 1 : last_;                       \
            float4 R1_ = srec[rn_];                                          \
            unsigned sp1_ = __builtin_amdgcn_readfirstlane(                  \
                                __float_as_uint(R1_.x));                     \
            float e1_ = (enc + ((sp1_ >> 12) << 4))[c];                      \
            for (; r_ < (hi); ++r_) {                                        \
                float4 Rc_ = R0_; float ec_ = e0_;                           \
                R0_ = R1_; e0_ = e1_;                                        \
                int rp_ = r_ + 2 < last_ ? r_ + 2 : last_;                   \
                R1_ = srec[rp_];                                             \
                unsigned spn_ = __builtin_amdgcn_readfirstlane(              \
                                    __float_as_uint(R1_.x));                 \
                e1_ = (enc + ((spn_ >> 12) << 4))[c];                        \
                PROC(Rc_, ec_, CZ1);                                         \
            }                                                                \
        }                                                                    \
    } while (0)

    RUNRANGE(rA, rM, true);    // bucket w:   cz=1, wzv = fz
    RUNRANGE(rM, rB, false);   // bucket w+1: cz=0, wzv = 1-fz

#undef RUNRANGE
#undef PROC

    __syncthreads();

    // Flush: contiguous wave-level pattern (lane-adjacent addresses).
    if (!multi) {
        const float4* t4 = (const float4*)tile;
        for (int i = tid; i < TILE_FL / 4; i += ACC_THREADS) {
            float4 v = t4[i];
            if (v.x == 0.f && v.y == 0.f && v.z == 0.f && v.w == 0.f) continue;
            int point = i >> 2;
            int q = (i & 3) << 2;
            int lx = point & 7, ly = (point >> 3) & 7, lz = point >> 6;
            size_t gf = (((size_t)((gz0 + lz) * GH + gy0 + ly)) * GW + gx0 + lx) * GC + q;
            *(float4*)&grid[gf] = v;
        }
    } else {
        for (int idx = tid; idx < TILE_FL; idx += ACC_THREADS) {
            float v = tile[idx];
            if (v == 0.f) continue;
            int point = idx >> 4, cc = idx & 15;
            int lx = point & 7, ly = (point >> 3) & 7, lz = point >> 6;
            unsafeAtomicAdd(
                &grid[(((gz0 + lz) * GH + gy0 + ly) * GW + gx0 + lx) * GC + cc], v);
        }
    }
}

// ---------------------------------------------------------------------------
// Fallback: direct atomic splat (round-1 kernel) if d_ws is too small.
__global__ __launch_bounds__(256) void splat_direct(
    const float* __restrict__ dirs, const float* __restrict__ orig,
    const float* __restrict__ nearv, const float* __restrict__ farv,
    const float* __restrict__ enc,
    float* __restrict__ grid, int n_rays)
{
    int gt = blockIdx.x * blockDim.x + threadIdx.x;
    int group = gt >> 4;
    int c = gt & 15;
    if (group >= n_rays * ST) return;
    int ray = group / ST;
    int s   = group - ray * ST;
    int ix, iy, iz; float fx, fy, fz;
    if (!compute_sample(dirs, orig, nearv, farv, ray, s, ix, iy, iz, fx, fy, fz))
        return;
    float ev = enc[ray * GC + c];
    float gx0 = 1.0f - fx, gy0 = 1.0f - fy, gz0 = 1.0f - fz;
    #pragma unroll
    for (int corner = 0; corner < 8; ++corner) {
        int cx = corner & 1, cy = (corner >> 1) & 1, cz = (corner >> 2) & 1;
        int jx = ix + cx, jy = iy + cy, jz = iz + cz;
        if (jx < 0 || jx >= GW || jy < 0 || jy >= GH || jz < 0 || jz >= GD) continue;
        float w = (cx ? fx : gx0) * (cy ? fy : gy0) * (cz ? fz : gz0);
        unsafeAtomicAdd(&grid[((jz * GH + jy) * GW + jx) * GC + c], w * ev);
    }
}

// ---------------------------------------------------------------------------
extern "C" void kernel_launch(void* const* d_in, const int* in_sizes, int n_in,
                              void* d_out, int out_size, void* d_ws, size_t ws_size,
                              hipStream_t stream) {
    const float* dirs  = (const float*)d_in[0];
    const float* orig  = (const float*)d_in[1];
    const float* nearv = (const float*)d_in[2];
    const float* farv  = (const float*)d_in[3];
    const float* enc   = (const float*)d_in[4];
    float* out = (float*)d_out;

    int n_rays = in_sizes[2];
    int total  = n_rays * ST;

    hipMemsetAsync(out, 0, (size_t)out_size * sizeof(float), stream);

    // Workspace layout: [counts|offsets|cursor|nck|chunk_info| (align16) recs]
    int cap = total + total / 2;                 // record capacity (~1.5x)
    int maxck = NBINS + cap / CHK + 2;           // chunk-table bound
    size_t prefix_ints = (size_t)NBINS * 3 + 1 + (size_t)maxck;
    prefix_ints = (prefix_ints + 3) & ~(size_t)3;        // align recs to 16 B
    size_t need = prefix_ints * 4 + (size_t)cap * 16;

    if (ws_size < need || n_rays >= (1 << 20)) {
        long long tthreads = (long long)total * 16;
        int blocks = (int)((tthreads + 255) / 256);
        splat_direct<<<blocks, 256, 0, stream>>>(dirs, orig, nearv, farv, enc,
                                                 out, n_rays);
        return;
    }

    int* counts  = (int*)d_ws;
    int* offsets = counts + NBINS;
    int* cursor  = offsets + NBINS;
    int* nck     = cursor + NBINS;
    unsigned int* chunk_info = (unsigned int*)(nck + 1);
    float4* recs = (float4*)((int*)d_ws + prefix_ints);

    hipMemsetAsync(counts, 0, NBINS * sizeof(int), stream);
    count_kernel<<<1024, 256, 0, stream>>>(dirs, orig, nearv, farv, counts, total);
    scan_kernel<<<1, 256, 0, stream>>>(counts, offsets, cursor, chunk_info, nck);
    scatter_kernel<<<(total + 255) / 256, 256, 0, stream>>>(
        dirs, orig, nearv, farv, cursor, recs, total, cap);
    accum_kernel<<<maxck, ACC_THREADS, 0, stream>>>(
        enc, offsets, counts, recs, chunk_info, nck, out);
}

// Round 17
// 231.353 us; speedup vs baseline: 3.3870x; 1.1194x over previous
//
#include <hip/hip_runtime.h>

// LightplaneSplatter: trilinear scatter-splat of per-ray encodings (C=16)
// into a (1,128,128,128,16) fp32 grid.
//
// Round 17: revert R16 (correctness regression, cause not identified);
// base = R15 (passing, 259us) with two low-risk changes:
//  (1) accum walk: 4-record batch ping-pong prefetch (A/B register sets, no
//      rotation moves). Theory: the R15 40% stall is enc L2-hit latency
//      (~200cy; enc is L2-resident -> invisible in FETCH_SIZE) plus srec
//      ds_read latency, both undercovered by R15's 1-deep prefetch.
//      PROC body is R15's verbatim known-good code.
//  (2) count_kernel grid 1024 -> 256: 4x fewer per-block histogram
//      init/drain ops and global atomics.

#define NS   64
#define NSI  8
#define ST   (NS + NSI)   // 72
#define GD   128
#define GH   128
#define GW   128
#define GC   16
#define DISP_INF 1e-4f

#define NTT   16                    // tiles per axis (8 points each)
#define NBINS (NTT * NTT * NTT)     // 4096
#define TILE_FL (8 * 8 * 8 * GC)    // 8192 floats = 32 KB
#define CHK   1024                  // samples per chunk
#define MULTI_FLAG 0x80000000u
#define ACC_THREADS 512             // 8 waves, one z-layer each

// ---------------------------------------------------------------------------
__device__ __forceinline__ bool compute_sample(
    const float* __restrict__ dirs, const float* __restrict__ orig,
    const float* __restrict__ nearv, const float* __restrict__ farv,
    int ray, int s,
    int& ix, int& iy, int& iz, float& fx, float& fy, float& fz)
{
    float nr = nearv[ray], fr = farv[ray];
    float t;
    if (s < NS) {
        float frac = ((float)s + 0.5f) * (1.0f / (float)NS);
        t = nr + (fr - nr) * frac;
    } else {
        float j    = (float)(s - NS + 1) * (1.0f / (float)NSI);
        float invf = 1.0f / fr;
        float disp = invf + (DISP_INF - invf) * j;
        t = 1.0f / disp;
    }
    float px = orig[ray*3+0] + t * dirs[ray*3+0];
    float py = orig[ray*3+1] + t * dirs[ray*3+1];
    float pz = orig[ray*3+2] + t * dirs[ray*3+2];
    float vx = (px + 1.0f) * 0.5f * 127.0f;
    float vy = (py + 1.0f) * 0.5f * 127.0f;
    float vz = (pz + 1.0f) * 0.5f * 127.0f;
    float bx = floorf(vx), by = floorf(vy), bz = floorf(vz);
    fx = vx - bx; fy = vy - by; fz = vz - bz;
    ix = (int)bx; iy = (int)by; iz = (int)bz;
    return !(ix < -1 || ix > GW - 1 ||
             iy < -1 || iy > GH - 1 ||
             iz < -1 || iz > GD - 1);
}

// Tile range touched by base cell i along one axis (i in [-1, 127]).
__device__ __forceinline__ void tile_range(int i, int& t0, int& t1)
{
    t0 = (i < 0 ? 0 : i) >> 3;
    t1 = (i + 1 > 127 ? 127 : i + 1) >> 3;
}

// ---------------------------------------------------------------------------
// Pass A: per-tile sample counts (with duplication for boundary footprints).
__global__ __launch_bounds__(256) void count_kernel(
    const float* __restrict__ dirs, const float* __restrict__ orig,
    const float* __restrict__ nearv, const float* __restrict__ farv,
    int* __restrict__ counts, int total)
{
    __shared__ int h[NBINS];
    for (int i = threadIdx.x; i < NBINS; i += 256) h[i] = 0;
    __syncthreads();
    for (int idx = blockIdx.x * 256 + threadIdx.x; idx < total;
         idx += gridDim.x * 256) {
        int ray = idx / ST, s = idx - (idx / ST) * ST;
        int ix, iy, iz; float fx, fy, fz;
        if (!compute_sample(dirs, orig, nearv, farv, ray, s, ix, iy, iz, fx, fy, fz))
            continue;
        int tx0, tx1, ty0, ty1, tz0, tz1;
        tile_range(ix, tx0, tx1); tile_range(iy, ty0, ty1); tile_range(iz, tz0, tz1);
        for (int tz = tz0; tz <= tz1; ++tz)
            for (int ty = ty0; ty <= ty1; ++ty)
                for (int tx = tx0; tx <= tx1; ++tx)
                    atomicAdd(&h[(tz * NTT + ty) * NTT + tx], 1);
    }
    __syncthreads();
    for (int i = threadIdx.x; i < NBINS; i += 256)
        if (h[i]) atomicAdd(&counts[i], h[i]);
}

// ---------------------------------------------------------------------------
// Pass B: scan counts -> offsets/cursor; emit chunk table.
__global__ __launch_bounds__(256) void scan_kernel(
    const int* __restrict__ counts, int* __restrict__ offsets,
    int* __restrict__ cursor, unsigned int* __restrict__ chunk_info,
    int* __restrict__ nck)
{
    __shared__ int p1[256], p2[256];
    const int CH = NBINS / 256;  // 16
    int tid = threadIdx.x;
    int base = tid * CH;
    int s1 = 0, s2 = 0;
    for (int i = 0; i < CH; ++i) {
        int c = counts[base + i];
        s1 += c;
        s2 += (c + CHK - 1) / CHK;
    }
    p1[tid] = s1; p2[tid] = s2;
    __syncthreads();
    if (tid == 0) {
        int a1 = 0, a2 = 0;
        for (int i = 0; i < 256; ++i) {
            int v1 = p1[i], v2 = p2[i];
            p1[i] = a1; p2[i] = a2;
            a1 += v1; a2 += v2;
        }
        nck[0] = a2;
    }
    __syncthreads();
    int run = p1[tid];
    int crun = p2[tid];
    for (int i = 0; i < CH; ++i) {
        int bin = base + i;
        int c = counts[bin];
        offsets[bin] = run;
        cursor[bin]  = run;
        int nc = (c + CHK - 1) / CHK;
        unsigned int mf = (nc > 1) ? MULTI_FLAG : 0u;
        for (int k = 0; k < nc; ++k)
            chunk_info[crun + k] = (unsigned int)bin | ((unsigned int)k << 12) | mf;
        crun += nc;
        run += c;
    }
}

// ---------------------------------------------------------------------------
// Pass C: scatter fat records into per-tile lists, wave-run aggregated.
// Record: float4 { uint pack = ray<<12 | (lz0+1)<<8 | (ly0+1)<<4 | (lx0+1),
//                  fx, fy, fz }  with l*0 = base cell relative to tile origin.
__global__ __launch_bounds__(256) void scatter_kernel(
    const float* __restrict__ dirs, const float* __restrict__ orig,
    const float* __restrict__ nearv, const float* __restrict__ farv,
    int* __restrict__ cursor, float4* __restrict__ recs, int total, int cap)
{
    int idx  = blockIdx.x * 256 + threadIdx.x;
    int lane = threadIdx.x & 63;
    bool act = (idx < total);

    int ix = 0, iy = 0, iz = 0; float fx = 0.f, fy = 0.f, fz = 0.f;
    int tx0 = 0, tx1 = -1, ty0 = 0, ty1 = -1, tz0 = 0, tz1 = -1;
    int ray = 0;
    if (act) {
        ray = idx / ST;
        int s = idx - ray * ST;
        if (compute_sample(dirs, orig, nearv, farv, ray, s, ix, iy, iz, fx, fy, fz)) {
            tile_range(ix, tx0, tx1);
            tile_range(iy, ty0, ty1);
            tile_range(iz, tz0, tz1);
        }
    }

    // Up to 8 footprint copies; same copy-index k across the wave so that
    // neighboring lanes (consecutive samples of a ray) form same-bin runs.
    #pragma unroll
    for (int kz = 0; kz < 2; ++kz)
    #pragma unroll
    for (int ky = 0; ky < 2; ++ky)
    #pragma unroll
    for (int kx = 0; kx < 2; ++kx) {
        int tzi = tz0 + kz, tyi = ty0 + ky, txi = tx0 + kx;
        int bin = (tzi <= tz1 && tyi <= ty1 && txi <= tx1)
                ? (tzi * NTT + tyi) * NTT + txi : -1;

        // Run detection: leader = first lane of a maximal same-bin run.
        int prev = __shfl_up(bin, 1, 64);
        bool leader = (lane == 0) || (bin != prev);
        unsigned long long lm = __ballot(leader);

        // My leader = highest set bit <= lane. (2ull<<63)-1 wraps to ~0ull.
        unsigned long long below = lm & ((2ull << lane) - 1ull);
        int lead = 63 - __clzll(below);

        int base = 0;
        if (leader && bin >= 0) {
            unsigned long long rest = (lane == 63) ? 0ull : (lm >> (lane + 1));
            int next = rest ? (lane + 1 + (__ffsll((long long)rest) - 1)) : 64;
            base = atomicAdd(&cursor[bin], next - lane);
        }
        base = __shfl(base, lead, 64);

        if (bin >= 0) {
            int slot = base + (lane - lead);
            if (slot < cap) {
                unsigned int pk = ((unsigned int)ray << 12)
                                | ((unsigned int)(iz - (tzi << 3) + 1) << 8)
                                | ((unsigned int)(iy - (tyi << 3) + 1) << 4)
                                |  (unsigned int)(ix - (txi << 3) + 1);
                recs[slot] = make_float4(__uint_as_float(pk), fx, fy, fz);
            }
        }
    }
}

// ---------------------------------------------------------------------------
// Bucket walk: records [lo,hi) of one z-bucket. 4-record batch ping-pong
// prefetch (A/B register sets, sentinel-clamped, no rotation moves).
// PROC semantics identical to R15 (known-good).
template<bool CZ1>
__device__ __forceinline__ void walk_bucket(
    const float* __restrict__ enc, const float4* srec, float* tile,
    int lo, int hi, int wzofs, int cx, int cy, int c, int dxm1, int dym1)
{
    if (lo >= hi) return;
    const int last = hi - 1;

    auto LD = [&](int j, float4& R, float& e) {
        int jj = j < last ? j : last;       // sentinel clamp
        R = srec[jj];
        unsigned sp = __float_as_uint(R.x); // wave-uniform (jj scalar)
        e = enc[((sp >> 12) << 4) + c];
    };
    auto PROCF = [&](const float4& Rc, float ev) {
        unsigned pk = __float_as_uint(Rc.x);
        int lx = (int)(pk & 15u) + dxm1;
        int ly = (int)((pk >> 4) & 15u) + dym1;
        if ((unsigned)(lx | ly) < 8u) {
            float wx = cx ? Rc.y : 1.0f - Rc.y;
            float wy = cy ? Rc.z : 1.0f - Rc.z;
            float wz = CZ1 ? Rc.w : 1.0f - Rc.w;
            int off = ((wzofs + (ly << 3) + lx) << 4) + c;
            tile[off] += (wx * wy) * (wz * ev);
        }
    };

    float4 A0, A1, A2, A3, B0, B1, B2, B3;
    float ea0, ea1, ea2, ea3, eb0, eb1, eb2, eb3;
    LD(lo,     A0, ea0); LD(lo + 1, A1, ea1);
    LD(lo + 2, A2, ea2); LD(lo + 3, A3, ea3);
    int g = lo;
    for (;;) {
        // Prefetch next batch into B while processing A.
        LD(g + 4, B0, eb0); LD(g + 5, B1, eb1);
        LD(g + 6, B2, eb2); LD(g + 7, B3, eb3);
        PROCF(A0, ea0);
        if (g + 1 < hi) PROCF(A1, ea1);
        if (g + 2 < hi) PROCF(A2, ea2);
        if (g + 3 < hi) PROCF(A3, ea3);
        g += 4;
        if (g >= hi) break;

        LD(g + 4, A0, ea0); LD(g + 5, A1, ea1);
        LD(g + 6, A2, ea2); LD(g + 7, A3, ea3);
        PROCF(B0, eb0);
        if (g + 1 < hi) PROCF(B1, eb1);
        if (g + 2 < hi) PROCF(B2, eb2);
        if (g + 3 < hi) PROCF(B3, eb3);
        g += 4;
        if (g >= hi) break;
    }
}

// ---------------------------------------------------------------------------
// Pass D: one block (8 z-slab waves) per chunk. Records counting-sorted by
// z-bucket (lz0+1 in [0,8]) in LDS; wave w walks buckets w (cz=1) and w+1
// (cz=0) via walk_bucket. One 64-lane plain LDS RMW per engaged record.
__global__ __launch_bounds__(ACC_THREADS, 6) void accum_kernel(
    const float* __restrict__ enc,
    const int* __restrict__ offsets, const int* __restrict__ counts,
    const float4* __restrict__ recs, const unsigned int* __restrict__ chunk_info,
    const int* __restrict__ nck,
    float* __restrict__ grid)
{
    if ((int)blockIdx.x >= nck[0]) return;
    unsigned int info = chunk_info[blockIdx.x];
    int bin  = (int)(info & 0xFFFu);
    int k    = (int)((info >> 12) & 0x7FFFFu);
    bool multi = (info & MULTI_FLAG) != 0;
    int cnt  = counts[bin];
    int start = offsets[bin] + k * CHK;
    int n = cnt - k * CHK; if (n > CHK) n = CHK;

    int tx = bin & 15, ty = (bin >> 4) & 15, tz = bin >> 8;
    int gx0 = tx << 3, gy0 = ty << 3, gz0 = tz << 3;

    __shared__ float  tile[TILE_FL];   // 32 KB
    __shared__ float4 srec[CHK];       // 16 KB (z-sorted records)
    __shared__ int zhist[9];
    __shared__ int zbase[10];
    __shared__ int zcur[9];

    int tid = threadIdx.x;
    {
        float4* t4 = (float4*)tile;
        #pragma unroll
        for (int i = tid; i < TILE_FL / 4; i += ACC_THREADS)
            t4[i] = make_float4(0.f, 0.f, 0.f, 0.f);
    }
    if (tid < 9) zhist[tid] = 0;
    __syncthreads();

    // Stage (coalesced) + z-bucket histogram. Each thread handles <=2 records.
    float4 Ra, Rb; int ba = -1, bb = -1;
    if (tid < n) {
        Ra = recs[start + tid];
        ba = (int)((__float_as_uint(Ra.x) >> 8) & 15u);
        atomicAdd(&zhist[ba], 1);
    }
    if (tid + ACC_THREADS < n) {
        Rb = recs[start + tid + ACC_THREADS];
        bb = (int)((__float_as_uint(Rb.x) >> 8) & 15u);
        atomicAdd(&zhist[bb], 1);
    }
    __syncthreads();
    if (tid == 0) {
        int a = 0;
        #pragma unroll
        for (int i = 0; i < 9; ++i) { zbase[i] = a; zcur[i] = a; a += zhist[i]; }
        zbase[9] = a;
    }
    __syncthreads();
    if (ba >= 0) { int p = atomicAdd(&zcur[ba], 1); srec[p] = Ra; }
    if (bb >= 0) { int p = atomicAdd(&zcur[bb], 1); srec[p] = Rb; }
    __syncthreads();

    // Wave w owns z-layer w. Bucket w: cz=1 (wzv = fz); bucket w+1: cz=0.
    int swz  = __builtin_amdgcn_readfirstlane(tid >> 6);
    int lane = tid & 63;
    int c2   = lane >> 4;               // xy-corner 0..3
    int cx   = c2 & 1, cy = c2 >> 1;
    int c    = lane & 15;               // channel
    int dxm1 = cx - 1, dym1 = cy - 1;   // per-lane decode offsets
    int wzofs = swz << 6;               // wz * 64 points (scalar)

    int rA = __builtin_amdgcn_readfirstlane(zbase[swz]);
    int rM = __builtin_amdgcn_readfirstlane(zbase[swz + 1]);
    int rB = __builtin_amdgcn_readfirstlane(zbase[swz + 2]);

    walk_bucket<true >(enc, srec, tile, rA, rM, wzofs, cx, cy, c, dxm1, dym1);
    walk_bucket<false>(enc, srec, tile, rM, rB, wzofs, cx, cy, c, dxm1, dym1);

    __syncthreads();

    // Flush: contiguous wave-level pattern (lane-adjacent addresses).
    if (!multi) {
        const float4* t4 = (const float4*)tile;
        for (int i = tid; i < TILE_FL / 4; i += ACC_THREADS) {
            float4 v = t4[i];
            if (v.x == 0.f && v.y == 0.f && v.z == 0.f && v.w == 0.f) continue;
            int point = i >> 2;
            int q = (i & 3) << 2;
            int lx = point & 7, ly = (point >> 3) & 7, lz = point >> 6;
            size_t gf = (((size_t)((gz0 + lz) * GH + gy0 + ly)) * GW + gx0 + lx) * GC + q;
            *(float4*)&grid[gf] = v;
        }
    } else {
        for (int idx = tid; idx < TILE_FL; idx += ACC_THREADS) {
            float v = tile[idx];
            if (v == 0.f) continue;
            int point = idx >> 4, cc = idx & 15;
            int lx = point & 7, ly = (point >> 3) & 7, lz = point >> 6;
            unsafeAtomicAdd(
                &grid[(((gz0 + lz) * GH + gy0 + ly) * GW + gx0 + lx) * GC + cc], v);
        }
    }
}

// ---------------------------------------------------------------------------
// Fallback: direct atomic splat (round-1 kernel) if d_ws is too small.
__global__ __launch_bounds__(256) void splat_direct(
    const float* __restrict__ dirs, const float* __restrict__ orig,
    const float* __restrict__ nearv, const float* __restrict__ farv,
    const float* __restrict__ enc,
    float* __restrict__ grid, int n_rays)
{
    int gt = blockIdx.x * blockDim.x + threadIdx.x;
    int group = gt >> 4;
    int c = gt & 15;
    if (group >= n_rays * ST) return;
    int ray = group / ST;
    int s   = group - ray * ST;
    int ix, iy, iz; float fx, fy, fz;
    if (!compute_sample(dirs, orig, nearv, farv, ray, s, ix, iy, iz, fx, fy, fz))
        return;
    float ev = enc[ray * GC + c];
    float gx0 = 1.0f - fx, gy0 = 1.0f - fy, gz0 = 1.0f - fz;
    #pragma unroll
    for (int corner = 0; corner < 8; ++corner) {
        int cx = corner & 1, cy = (corner >> 1) & 1, cz = (corner >> 2) & 1;
        int jx = ix + cx, jy = iy + cy, jz = iz + cz;
        if (jx < 0 || jx >= GW || jy < 0 || jy >= GH || jz < 0 || jz >= GD) continue;
        float w = (cx ? fx : gx0) * (cy ? fy : gy0) * (cz ? fz : gz0);
        unsafeAtomicAdd(&grid[((jz * GH + jy) * GW + jx) * GC + c], w * ev);
    }
}

// ---------------------------------------------------------------------------
extern "C" void kernel_launch(void* const* d_in, const int* in_sizes, int n_in,
                              void* d_out, int out_size, void* d_ws, size_t ws_size,
                              hipStream_t stream) {
    const float* dirs  = (const float*)d_in[0];
    const float* orig  = (const float*)d_in[1];
    const float* nearv = (const float*)d_in[2];
    const float* farv  = (const float*)d_in[3];
    const float* enc   = (const float*)d_in[4];
    float* out = (float*)d_out;

    int n_rays = in_sizes[2];
    int total  = n_rays * ST;

    hipMemsetAsync(out, 0, (size_t)out_size * sizeof(float), stream);

    // Workspace layout: [counts|offsets|cursor|nck|chunk_info| (align16) recs]
    int cap = total + total / 2;                 // record capacity (~1.5x)
    int maxck = NBINS + cap / CHK + 2;           // chunk-table bound
    size_t prefix_ints = (size_t)NBINS * 3 + 1 + (size_t)maxck;
    prefix_ints = (prefix_ints + 3) & ~(size_t)3;        // align recs to 16 B
    size_t need = prefix_ints * 4 + (size_t)cap * 16;

    if (ws_size < need || n_rays >= (1 << 20)) {
        long long tthreads = (long long)total * 16;
        int blocks = (int)((tthreads + 255) / 256);
        splat_direct<<<blocks, 256, 0, stream>>>(dirs, orig, nearv, farv, enc,
                                                 out, n_rays);
        return;
    }

    int* counts  = (int*)d_ws;
    int* offsets = counts + NBINS;
    int* cursor  = offsets + NBINS;
    int* nck     = cursor + NBINS;
    unsigned int* chunk_info = (unsigned int*)(nck + 1);
    float4* recs = (float4*)((int*)d_ws + prefix_ints);

    hipMemsetAsync(counts, 0, NBINS * sizeof(int), stream);
    count_kernel<<<256, 256, 0, stream>>>(dirs, orig, nearv, farv, counts, total);
    scan_kernel<<<1, 256, 0, stream>>>(counts, offsets, cursor, chunk_info, nck);
    scatter_kernel<<<(total + 255) / 256, 256, 0, stream>>>(
        dirs, orig, nearv, farv, cursor, recs, total, cap);
    accum_kernel<<<maxck, ACC_THREADS, 0, stream>>>(
        enc, offsets, counts, recs, chunk_info, nck, out);
}